// Round 4
// baseline (1516.560 us; speedup 1.0000x reference)
//
#include <hip/hip_runtime.h>
#include <cstdint>
#include <cstddef>

typedef __attribute__((ext_vector_type(8))) short short8_t;
typedef __attribute__((ext_vector_type(4))) float f32x4;

#define DEV __device__ __forceinline__

DEV unsigned short f2bf(float f) {
    unsigned u = __float_as_uint(f);
    u += 0x7FFFu + ((u >> 16) & 1u);   // round-to-nearest-even
    return (unsigned short)(u >> 16);
}

// ---------------------------------------------------------------------------
// Weight packing: fp32 row-major (K x N) -> bf16 MFMA-B fragment order.
// chunk c (8 elems, 16B): lane = c&63, tkb = c>>6, kb = tkb % (K/32),
// t = tkb / (K/32);  elem j: k = kb*32 + (lane>>4)*8 + j, n = t*16 + (lane&15)
// ---------------------------------------------------------------------------
__global__ void pack_weights(const float* W1, const float* W2,
                             const float* Wp1, const float* Wp2,
                             const float* Ws1, const float* Ws2, const float* Ws3,
                             const float* Wg1, const float* Wg2, const float* Wg3,
                             const float* Wgate, unsigned short* out)
{
    int c = blockIdx.x * 256 + threadIdx.x;
    if (c >= 176640) return;
    const float* src; int K, N; size_t dstoff; int lc = c;
    if      (c <  16384) { src = W1;  K=256; N=512; dstoff = 0; }
    else if (c <  32768) { lc = c-16384;  src = W2;  K=512; N=256; dstoff = 131072; }
    else if (c <  98304) { lc = c-32768;  int p = lc/8192; lc -= p*8192;
                           src = Wp1 + (size_t)p*65536; K=256; N=256;
                           dstoff = 262144 + (size_t)p*65536; }
    else if (c < 110592) { lc = c-98304;  int p = lc/1536; lc -= p*1536;
                           src = Wp2 + (size_t)p*10240; K=256; N=40;
                           dstoff = 786432 + (size_t)p*12288; }
    else if (c < 126976) { lc = c-110592; src = Ws1; K=256; N=512; dstoff = 884736; }
    else if (c < 143360) { lc = c-126976; src = Ws2; K=512; N=256; dstoff = 1015808; }
    else if (c < 147456) { lc = c-143360; src = Ws3; K=256; N=128; dstoff = 1146880; }
    else if (c < 155648) { lc = c-147456; src = Wg1; K=128; N=512; dstoff = 1179648; }
    else if (c < 172032) { lc = c-155648; src = Wg2; K=512; N=256; dstoff = 1245184; }
    else if (c < 176128) { lc = c-172032; src = Wg3; K=256; N=128; dstoff = 1376256; }
    else                 { lc = c-176128; src = Wgate; K=256; N=8;  dstoff = 1409024; }
    int lane = lc & 63, tkb = lc >> 6;
    int KB = K >> 5;
    int kb = tkb % KB, t = tkb / KB;
    int n  = t*16 + (lane & 15);
    int k0 = kb*32 + (lane >> 4)*8;
    unsigned short e[8];
#pragma unroll
    for (int j = 0; j < 8; ++j) {
        float v = (n < N) ? src[(size_t)(k0 + j)*N + n] : 0.f;
        e[j] = f2bf(v);
    }
    uint4 o;
    o.x = (unsigned)e[0] | ((unsigned)e[1] << 16);
    o.y = (unsigned)e[2] | ((unsigned)e[3] << 16);
    o.z = (unsigned)e[4] | ((unsigned)e[5] << 16);
    o.w = (unsigned)e[6] | ((unsigned)e[7] << 16);
    *reinterpret_cast<uint4*>(out + dstoff + (size_t)lc*8) = o;
}

// ---------------------------------------------------------------------------
struct Params {
    const float *obs, *actions;
    const float *b1, *b2, *bp1, *bp2, *bs1, *bs2, *bs3, *bg1, *bg2, *bg3, *bgate;
    const unsigned short *W1p, *W2p, *Wp1p, *Wp2p, *Ws1p, *Ws2p, *Ws3p,
                         *Wg1p, *Wg2p, *Wg3p, *Wgatep;
    float* out;
};

// One 16-row slab (rows row0..row0+15 of the LDS tile), NTW n-tiles, NMT=1.
// A from LDS bf16 (stride xs), B from packed global weights.
template<int NTW, int NKB>
DEV void mfma_slab(const unsigned short* X, int xs, int row0,
                   const unsigned short* wp, int nkbtot, int kbstart, int nt0,
                   f32x4 (&acc)[NTW])
{
    const int lane = threadIdx.x & 63;
    const int q = lane >> 4, r = lane & 15;
#pragma unroll
    for (int kb = 0; kb < NKB; ++kb) {
        short8_t a = *reinterpret_cast<const short8_t*>(X + (row0 + r)*xs + kb*32 + q*8);
#pragma unroll
        for (int t = 0; t < NTW; ++t) {
            short8_t b = *reinterpret_cast<const short8_t*>(
                wp + ((size_t)((nt0 + t)*nkbtot + kbstart + kb)*64 + lane)*8);
            acc[t] = __builtin_amdgcn_mfma_f32_16x16x32_bf16(a, b, acc[t], 0, 0, 0);
        }
    }
}

// Same, but A-fragments built directly from fp32 obs (global), cols colbase+...
template<int NTW, int NKB>
DEV void mfma_slab_obsA(const float* obs, int rowg0, int colbase,
                        const unsigned short* wp, int nkbtot, int nt0,
                        f32x4 (&acc)[NTW])
{
    const int lane = threadIdx.x & 63;
    const int q = lane >> 4, r = lane & 15;
    const int rowg = rowg0 + r;
    const bool ok = rowg < 65536;
#pragma unroll
    for (int kb = 0; kb < NKB; ++kb) {
        float4 v0 = {0.f,0.f,0.f,0.f}, v1 = {0.f,0.f,0.f,0.f};
        if (ok) {
            const float* s = obs + (size_t)rowg*384 + colbase + kb*32 + q*8;
            v0 = *reinterpret_cast<const float4*>(s);
            v1 = *reinterpret_cast<const float4*>(s + 4);
        }
        short8_t a = { (short)f2bf(v0.x), (short)f2bf(v0.y), (short)f2bf(v0.z), (short)f2bf(v0.w),
                       (short)f2bf(v1.x), (short)f2bf(v1.y), (short)f2bf(v1.z), (short)f2bf(v1.w) };
#pragma unroll
        for (int t = 0; t < NTW; ++t) {
            short8_t b = *reinterpret_cast<const short8_t*>(
                wp + ((size_t)((nt0 + t)*nkbtot + kb)*64 + lane)*8);
            acc[t] = __builtin_amdgcn_mfma_f32_16x16x32_bf16(a, b, acc[t], 0, 0, 0);
        }
    }
}

// store one n-tile of one slab to bf16 LDS, bias + optional leaky-relu
DEV void store1(const f32x4& a, unsigned short* dst, int xs, int row0, int col0,
                const float* bias, int bcol0, bool lrelu)
{
    const int lane = threadIdx.x & 63;
    const int q = lane >> 4, r = lane & 15;
    float bv = bias[bcol0 + r];
#pragma unroll
    for (int i = 0; i < 4; ++i) {
        float v = a[i] + bv;
        if (lrelu) v = v > 0.f ? v : 0.01f*v;
        dst[(size_t)(row0 + q*4 + i)*xs + col0 + r] = f2bf(v);
    }
}

// ---------------------------------------------------------------------------
// 384 threads = 6 waves, 48 batch rows per block (3 slabs x 16).
// wave -> (slab = wave>>1, half = wave&1); GEMM coverage: NTW=8 tiles/wave.
// LDS 77568 B -> 2 blocks/CU -> 12 waves/CU. (384,3): cap 170 regs, no spill.
#define ROWS 48
#define XS   264
__global__ __launch_bounds__(384, 3) void actor_fused(Params p)
{
    __shared__ __align__(16) unsigned char smem[77568];
    unsigned short* xStat   = (unsigned short*)(smem);           // 48x264 bf16, later bufA
    unsigned short* bufA    = (unsigned short*)(smem);           // s1' (alias, written at end of s1 chain)
    unsigned short* halfbuf = (unsigned short*)(smem + 25344);   // 48x264 bf16
    unsigned short* sg      = (unsigned short*)(smem + 50688);   // 48x264 bf16 (cols 0..255)
    float*          psbuf   = (float*)(smem + 50688);            // 48x48 f32 (alias sg, post-gate)
    float*          sums    = (float*)(smem + 50688 + 9216);     // 48x40 f32 (alias sg)
    float*          wgate   = (float*)(smem + 76032);            // 48x8 f32

    const int tid  = threadIdx.x;
    const int wave = tid >> 6;
    const int slab = wave >> 1;      // 0..2
    const int half = wave & 1;       // 0..1
    const int lane = tid & 63, q = lane >> 4, r = lane & 15;
    const int b0   = blockIdx.x * ROWS;

    // ---- P1: load obs stat cols -> bf16 LDS --------------------------------
    for (int i = tid; i < ROWS*64; i += 384) {
        int rr = i >> 6, c4 = i & 63;
        float4 v = {0.f,0.f,0.f,0.f};
        if (b0 + rr < 65536)
            v = *reinterpret_cast<const float4*>(p.obs + (size_t)(b0 + rr)*384 + c4*4);
        unsigned short* d = xStat + rr*XS + c4*4;
        d[0]=f2bf(v.x); d[1]=f2bf(v.y); d[2]=f2bf(v.z); d[3]=f2bf(v.w);
    }
    __syncthreads();

    // ---- G2 chain: obs-goal -> Wg1 -> Wg2 -> Wg3 -> sg[:,128:256] ----------
    {
        f32x4 acc[8] = {};
        for (int h = 0; h < 2; ++h) {
            f32x4 t[8] = {};
            mfma_slab_obsA<8,4>(p.obs, b0 + slab*16, 256, p.Wg1p, 4, 16*h + 8*half, t);
            __syncthreads();
#pragma unroll
            for (int j = 0; j < 8; ++j)
                store1(t[j], halfbuf, XS, slab*16, (8*half+j)*16, p.bg1 + 256*h, (8*half+j)*16, true);
            __syncthreads();
            mfma_slab<8,8>(halfbuf, XS, slab*16, p.Wg2p, 16, 8*h, 8*half, acc);
        }
        __syncthreads();
#pragma unroll
        for (int j = 0; j < 8; ++j)
            store1(acc[j], halfbuf, XS, slab*16, (8*half+j)*16, p.bg2, (8*half+j)*16, true);
        __syncthreads();
        f32x4 g3[4] = {};
        mfma_slab<4,8>(halfbuf, XS, slab*16, p.Wg3p, 8, 0, 4*half, g3);
#pragma unroll
        for (int j = 0; j < 4; ++j)
            store1(g3[j], sg, XS, slab*16, 128 + (4*half+j)*16, p.bg3, (4*half+j)*16, true);
    }
    __syncthreads();

    // ---- S2 chain: xStat -> Ws1 -> Ws2 -> Ws3 -> sg[:,0:128] ---------------
    {
        f32x4 acc[8] = {};
        for (int h = 0; h < 2; ++h) {
            f32x4 t[8] = {};
            mfma_slab<8,8>(xStat, XS, slab*16, p.Ws1p, 8, 0, 16*h + 8*half, t);
            __syncthreads();
#pragma unroll
            for (int j = 0; j < 8; ++j)
                store1(t[j], halfbuf, XS, slab*16, (8*half+j)*16, p.bs1 + 256*h, (8*half+j)*16, true);
            __syncthreads();
            mfma_slab<8,8>(halfbuf, XS, slab*16, p.Ws2p, 16, 8*h, 8*half, acc);
        }
        __syncthreads();
#pragma unroll
        for (int j = 0; j < 8; ++j)
            store1(acc[j], halfbuf, XS, slab*16, (8*half+j)*16, p.bs2, (8*half+j)*16, true);
        __syncthreads();
        f32x4 s3[4] = {};
        mfma_slab<4,8>(halfbuf, XS, slab*16, p.Ws3p, 8, 0, 4*half, s3);
#pragma unroll
        for (int j = 0; j < 4; ++j)
            store1(s3[j], sg, XS, slab*16, (4*half+j)*16, p.bs3, (4*half+j)*16, true);
    }
    __syncthreads();

    // ---- Gate: w_gate = exp(sg@Wgate + bgate), waves 0..2 ------------------
    if (wave < 3) {
        f32x4 g[1] = {};
        mfma_slab<1,8>(sg, XS, wave*16, p.Wgatep, 8, 0, 0, g);
        if (r < 8) {
            float bv = p.bgate[r];
#pragma unroll
            for (int i = 0; i < 4; ++i)
                wgate[(wave*16 + q*4 + i)*8 + r] = expf(g[0][i] + bv);
        }
    }
    __syncthreads();

    // ---- S1 chain: xStat -> W1 -> W2 -> bufA (aliases xStat; stored last) --
    {
        f32x4 acc[8] = {};
        for (int h = 0; h < 2; ++h) {
            f32x4 t[8] = {};
            mfma_slab<8,8>(xStat, XS, slab*16, p.W1p, 8, 0, 16*h + 8*half, t);
            __syncthreads();
#pragma unroll
            for (int j = 0; j < 8; ++j)
                store1(t[j], halfbuf, XS, slab*16, (8*half+j)*16, p.b1 + 256*h, (8*half+j)*16, true);
            __syncthreads();
            mfma_slab<8,8>(halfbuf, XS, slab*16, p.W2p, 16, 8*h, 8*half, acc);
        }
        __syncthreads();   // all xStat & halfbuf reads done -> safe to overwrite xStat with bufA
#pragma unroll
        for (int j = 0; j < 8; ++j)
            store1(acc[j], bufA, XS, slab*16, (8*half+j)*16, p.b2, (8*half+j)*16, true);
    }
    // sums init (aliases sg region; gate reads finished at gate barrier)
    for (int i = tid; i < ROWS*40; i += 384) sums[i] = 0.f;
    __syncthreads();

    // ---- Primitives: h=lrelu(bufA@Wp1+bp1); ps=h@Wp2+bp2; mixture ----------
    for (int pp = 0; pp < 8; ++pp) {
        f32x4 th[8] = {};
        mfma_slab<8,8>(bufA, XS, slab*16, p.Wp1p + (size_t)pp*65536, 8, 0, 8*half, th);
        __syncthreads();
#pragma unroll
        for (int j = 0; j < 8; ++j)
            store1(th[j], halfbuf, XS, slab*16, (8*half+j)*16, p.bp1 + pp*256, (8*half+j)*16, true);
        __syncthreads();
        if (wave < 3) {
            f32x4 aps[3] = {};
            mfma_slab<3,8>(halfbuf, XS, wave*16, p.Wp2p + pp*12288, 8, 0, 0, aps);
#pragma unroll
            for (int t = 0; t < 3; ++t) {
                int col = t*16 + r;
                if (col < 40) {
                    float bv = p.bp2[pp*40 + col];
#pragma unroll
                    for (int i = 0; i < 4; ++i)
                        psbuf[(wave*16 + q*4 + i)*48 + col] = aps[t][i] + bv;
                }
            }
        }
        __syncthreads();
        for (int i = tid; i < ROWS*20; i += 384) {
            int b = i / 20, j = i - b*20;
            float inv = wgate[b*8 + pp] * expf(-psbuf[b*48 + 20 + j]);
            sums[b*40 + j]      += psbuf[b*48 + j] * inv;
            sums[b*40 + 20 + j] += inv;
        }
        __syncthreads();
    }

    // ---- Output: log_prob / entropy ----------------------------------------
    if (tid < ROWS) {
        int gb = b0 + tid;
        if (gb < 65536) {
            float lp = 0.f, sl = 0.f;
#pragma unroll
            for (int j = 0; j < 20; ++j) {
                float s2v = sums[tid*40 + 20 + j];
                float s1v = sums[tid*40 + j];
                float av  = p.actions[(size_t)gb*20 + j];
                float z   = av*s2v - s1v;          // (a - mu)/sigma
                float L   = logf(s2v);             // -log_sigma
                lp += -0.5f*z*z + L;
                sl += L;
            }
            p.out[(size_t)gb*2 + 0] = lp - 20.f*0.91893853320467274f;
            p.out[(size_t)gb*2 + 1] = 20.f*1.41893853320467274f - sl;
        }
    }
}

// ---------------------------------------------------------------------------
extern "C" void kernel_launch(void* const* d_in, const int* in_sizes, int n_in,
                              void* d_out, int out_size, void* d_ws, size_t ws_size,
                              hipStream_t stream)
{
    const float* obs     = (const float*)d_in[0];
    const float* actions = (const float*)d_in[1];
    const float* W1  = (const float*)d_in[2];  const float* b1  = (const float*)d_in[3];
    const float* W2  = (const float*)d_in[4];  const float* b2  = (const float*)d_in[5];
    const float* Wp1 = (const float*)d_in[6];  const float* bp1 = (const float*)d_in[7];
    const float* Wp2 = (const float*)d_in[8];  const float* bp2 = (const float*)d_in[9];
    const float* Ws1 = (const float*)d_in[10]; const float* bs1 = (const float*)d_in[11];
    const float* Ws2 = (const float*)d_in[12]; const float* bs2 = (const float*)d_in[13];
    const float* Ws3 = (const float*)d_in[14]; const float* bs3 = (const float*)d_in[15];
    const float* Wg1 = (const float*)d_in[16]; const float* bg1 = (const float*)d_in[17];
    const float* Wg2 = (const float*)d_in[18]; const float* bg2 = (const float*)d_in[19];
    const float* Wg3 = (const float*)d_in[20]; const float* bg3 = (const float*)d_in[21];
    const float* Wgate = (const float*)d_in[22]; const float* bgate = (const float*)d_in[23];

    unsigned short* wp = (unsigned short*)d_ws;

    pack_weights<<<690, 256, 0, stream>>>(W1, W2, Wp1, Wp2, Ws1, Ws2, Ws3,
                                          Wg1, Wg2, Wg3, Wgate, wp);

    Params P;
    P.obs = obs; P.actions = actions; P.out = (float*)d_out;
    P.b1 = b1; P.b2 = b2; P.bp1 = bp1; P.bp2 = bp2;
    P.bs1 = bs1; P.bs2 = bs2; P.bs3 = bs3;
    P.bg1 = bg1; P.bg2 = bg2; P.bg3 = bg3; P.bgate = bgate;
    P.W1p = wp;            P.W2p = wp + 131072;  P.Wp1p = wp + 262144;
    P.Wp2p = wp + 786432;  P.Ws1p = wp + 884736; P.Ws2p = wp + 1015808;
    P.Ws3p = wp + 1146880; P.Wg1p = wp + 1179648; P.Wg2p = wp + 1245184;
    P.Wg3p = wp + 1376256; P.Wgatep = wp + 1409024;

    actor_fused<<<(65536 + ROWS - 1)/ROWS, 384, 0, stream>>>(P);
}

// Round 5
// 496.686 us; speedup vs baseline: 3.0534x; 3.0534x over previous
//
#include <hip/hip_runtime.h>
#include <cstdint>
#include <cstddef>

typedef __attribute__((ext_vector_type(8))) short short8_t;
typedef __attribute__((ext_vector_type(4))) float f32x4;

#define DEV __device__ __forceinline__

DEV unsigned short f2bf(float f) {
    unsigned u = __float_as_uint(f);
    u += 0x7FFFu + ((u >> 16) & 1u);   // round-to-nearest-even
    return (unsigned short)(u >> 16);
}

// ---------------------------------------------------------------------------
// Weight packing: fp32 row-major (K x N) -> bf16 MFMA-B fragment order.
// chunk c (8 elems, 16B): lane = c&63, tkb = c>>6, kb = tkb % (K/32),
// t = tkb / (K/32);  elem j: k = kb*32 + (lane>>4)*8 + j, n = t*16 + (lane&15)
// ---------------------------------------------------------------------------
__global__ void pack_weights(const float* W1, const float* W2,
                             const float* Wp1, const float* Wp2,
                             const float* Ws1, const float* Ws2, const float* Ws3,
                             const float* Wg1, const float* Wg2, const float* Wg3,
                             const float* Wgate, unsigned short* out)
{
    int c = blockIdx.x * 256 + threadIdx.x;
    if (c >= 176640) return;
    const float* src; int K, N; size_t dstoff; int lc = c;
    if      (c <  16384) { src = W1;  K=256; N=512; dstoff = 0; }
    else if (c <  32768) { lc = c-16384;  src = W2;  K=512; N=256; dstoff = 131072; }
    else if (c <  98304) { lc = c-32768;  int p = lc/8192; lc -= p*8192;
                           src = Wp1 + (size_t)p*65536; K=256; N=256;
                           dstoff = 262144 + (size_t)p*65536; }
    else if (c < 110592) { lc = c-98304;  int p = lc/1536; lc -= p*1536;
                           src = Wp2 + (size_t)p*10240; K=256; N=40;
                           dstoff = 786432 + (size_t)p*12288; }
    else if (c < 126976) { lc = c-110592; src = Ws1; K=256; N=512; dstoff = 884736; }
    else if (c < 143360) { lc = c-126976; src = Ws2; K=512; N=256; dstoff = 1015808; }
    else if (c < 147456) { lc = c-143360; src = Ws3; K=256; N=128; dstoff = 1146880; }
    else if (c < 155648) { lc = c-147456; src = Wg1; K=128; N=512; dstoff = 1179648; }
    else if (c < 172032) { lc = c-155648; src = Wg2; K=512; N=256; dstoff = 1245184; }
    else if (c < 176128) { lc = c-172032; src = Wg3; K=256; N=128; dstoff = 1376256; }
    else                 { lc = c-176128; src = Wgate; K=256; N=8;  dstoff = 1409024; }
    int lane = lc & 63, tkb = lc >> 6;
    int KB = K >> 5;
    int kb = tkb % KB, t = tkb / KB;
    int n  = t*16 + (lane & 15);
    int k0 = kb*32 + (lane >> 4)*8;
    unsigned short e[8];
#pragma unroll
    for (int j = 0; j < 8; ++j) {
        float v = (n < N) ? src[(size_t)(k0 + j)*N + n] : 0.f;
        e[j] = f2bf(v);
    }
    uint4 o;
    o.x = (unsigned)e[0] | ((unsigned)e[1] << 16);
    o.y = (unsigned)e[2] | ((unsigned)e[3] << 16);
    o.z = (unsigned)e[4] | ((unsigned)e[5] << 16);
    o.w = (unsigned)e[6] | ((unsigned)e[7] << 16);
    *reinterpret_cast<uint4*>(out + dstoff + (size_t)lc*8) = o;
}

// ---------------------------------------------------------------------------
struct Params {
    const float *obs, *actions;
    const float *b1, *b2, *bp1, *bp2, *bs1, *bs2, *bs3, *bg1, *bg2, *bg3, *bgate;
    const unsigned short *W1p, *W2p, *Wp1p, *Wp2p, *Ws1p, *Ws2p, *Ws3p,
                         *Wg1p, *Wg2p, *Wg3p, *Wgatep;
    float* out;
};

// A from LDS (bf16, stride xs elems = multiple of 8), B from packed global.
// All hot-loop indexing in 32-bit, flat short8 (16-byte) units so the compiler
// can fold (t,kb) into immediates instead of 64-bit per-access address chains
// (round-2 evidence: size_t math here -> ~20-30 VGPRs of addresses -> spills
// under the (512,4) 128-reg budget).
template<int NTW, int NMT, int NKB>
DEV void mfma_tiles(const unsigned short* X, int xs,
                    const unsigned short* wp, int nkbtot, int kbstart,
                    int nt0, f32x4 (&acc)[NTW][NMT])
{
    const int lane = threadIdx.x & 63;
    const int q = lane >> 4, r = lane & 15;
    const short8_t* __restrict__ W8 = (const short8_t*)wp;
    const short8_t* __restrict__ X8 = (const short8_t*)X;
    const int xrow = xs >> 3;                       // row stride in 16B units
    const int bbase = (nt0*nkbtot + kbstart)*64 + lane;
#pragma unroll
    for (int kb = 0; kb < NKB; ++kb) {
        short8_t a[NMT];
#pragma unroll
        for (int mt = 0; mt < NMT; ++mt)
            a[mt] = X8[(r + 16*mt)*xrow + kb*4 + q];
#pragma unroll
        for (int t = 0; t < NTW; ++t) {
            short8_t b = W8[bbase + (t*nkbtot + kb)*64];
#pragma unroll
            for (int mt = 0; mt < NMT; ++mt)
                acc[t][mt] = __builtin_amdgcn_mfma_f32_16x16x32_bf16(a[mt], b, acc[t][mt], 0, 0, 0);
        }
    }
}

// store one n-tile (both m-tiles) to bf16 LDS, bias + optional leaky-relu
DEV void store2_bf16(const f32x4 (&a)[2], unsigned short* dst, int os, int col0,
                     const float* bias, int Nreal, bool lrelu)
{
    const int lane = threadIdx.x & 63;
    const int q = lane >> 4, r = lane & 15;
    const int col = col0 + r;
    float bv = (col < Nreal) ? bias[col] : 0.f;
#pragma unroll
    for (int mt = 0; mt < 2; ++mt)
#pragma unroll
        for (int i = 0; i < 4; ++i) {
            float v = a[mt][i] + bv;
            if (lrelu) v = v > 0.f ? v : 0.01f*v;
            dst[(mt*16 + q*4 + i)*os + col] = f2bf(v);
        }
}

// ---------------------------------------------------------------------------
// 512 threads = 8 waves per block, 32 batch rows per block.
// LDS 59392 B -> 2 blocks/CU -> 16 waves/CU resident.
// (512,4): hard 128-reg unified budget. This is the ONLY tier that reached
// 16 waves/CU (R2); looser budgets let AGPR use exceed 128/wave -> 8 waves
// (R1/R3). The mfma_tiles 32-bit addressing removes R2's 32B/thread spill.
__global__ __launch_bounds__(512, 4) void actor_fused(Params p)
{
    __shared__ __align__(16) unsigned char smem[59392];
    unsigned short* xStat   = (unsigned short*)(smem);           // 32 x 264 bf16
    unsigned short* sg      = (unsigned short*)(smem);           // 32 x 264 bf16 (cols 0..255)
    float*          sums    = (float*)(smem);                    // 32 x 40 f32
    unsigned short* xGoal   = (unsigned short*)(smem + 16896);   // 32 x 136 bf16
    float*          psbuf   = (float*)(smem + 16896);            // 32 x 48 f32
    float*          wgate   = (float*)(smem + 23040);            // 32 x 8 f32
    unsigned short* halfbuf = (unsigned short*)(smem + 25600);   // 32 x 264 bf16
    unsigned short* bufA    = (unsigned short*)(smem + 42496);   // 32 x 264 bf16 (s1')

    const int tid  = threadIdx.x;
    const int wave = tid >> 6;
    const int b0   = blockIdx.x * 32;

    // ---- P1: load obs tile -> bf16 LDS -------------------------------------
    for (int i = tid; i < 32*96; i += 512) {
        int rr = i / 96, c4 = i - rr*96;
        const float4 v = *reinterpret_cast<const float4*>(p.obs + (size_t)(b0 + rr)*384 + c4*4);
        unsigned short e0 = f2bf(v.x), e1 = f2bf(v.y), e2 = f2bf(v.z), e3 = f2bf(v.w);
        unsigned short* d;
        if (c4 < 64) d = xStat + rr*264 + c4*4;
        else         d = xGoal + rr*136 + (c4 - 64)*4;
        d[0] = e0; d[1] = e1; d[2] = e2; d[3] = e3;
    }
    __syncthreads();

    // ---- P2: s1' = lrelu(lrelu(xStat@W1+b1)@W2+b2) -> bufA (K-split 512) ---
    f32x4 acc1[2][2] = {};
    for (int h = 0; h < 2; ++h) {
        f32x4 t1[2][2] = {};
        mfma_tiles<2,2,8>(xStat, 264, p.W1p, 8, 0, 16*h + 2*wave, t1);
        __syncthreads();
#pragma unroll
        for (int t = 0; t < 2; ++t)
            store2_bf16(t1[t], halfbuf, 264, (2*wave + t)*16, p.b1 + 256*h, 256, true);
        __syncthreads();
        mfma_tiles<2,2,8>(halfbuf, 264, p.W2p, 16, 8*h, 2*wave, acc1);
    }
    __syncthreads();
#pragma unroll
    for (int t = 0; t < 2; ++t)
        store2_bf16(acc1[t], bufA, 264, (2*wave + t)*16, p.b2, 256, true);

    // ---- P3: s2 chain -> sg[:, 0:128] --------------------------------------
    f32x4 acc2[2][2] = {};
    for (int h = 0; h < 2; ++h) {
        f32x4 t2[2][2] = {};
        mfma_tiles<2,2,8>(xStat, 264, p.Ws1p, 8, 0, 16*h + 2*wave, t2);
        __syncthreads();
#pragma unroll
        for (int t = 0; t < 2; ++t)
            store2_bf16(t2[t], halfbuf, 264, (2*wave + t)*16, p.bs1 + 256*h, 256, true);
        __syncthreads();
        mfma_tiles<2,2,8>(halfbuf, 264, p.Ws2p, 16, 8*h, 2*wave, acc2);
    }
    __syncthreads();
#pragma unroll
    for (int t = 0; t < 2; ++t)
        store2_bf16(acc2[t], halfbuf, 264, (2*wave + t)*16, p.bs2, 256, true);  // s2_2
    __syncthreads();
    {
        f32x4 a3[1][2] = {};
        mfma_tiles<1,2,8>(halfbuf, 264, p.Ws3p, 8, 0, wave, a3);
        store2_bf16(a3[0], sg, 264, wave*16, p.bs3, 128, true);     // lrelu(concat)
    }

    // ---- P4: g2 chain -> sg[:, 128:256] ------------------------------------
    f32x4 acc4[2][2] = {};
    for (int h = 0; h < 2; ++h) {
        f32x4 t3[2][2] = {};
        mfma_tiles<2,2,4>(xGoal, 136, p.Wg1p, 4, 0, 16*h + 2*wave, t3);
        __syncthreads();
#pragma unroll
        for (int t = 0; t < 2; ++t)
            store2_bf16(t3[t], halfbuf, 264, (2*wave + t)*16, p.bg1 + 256*h, 256, true);
        __syncthreads();
        mfma_tiles<2,2,8>(halfbuf, 264, p.Wg2p, 16, 8*h, 2*wave, acc4);
    }
    __syncthreads();
#pragma unroll
    for (int t = 0; t < 2; ++t)
        store2_bf16(acc4[t], halfbuf, 264, (2*wave + t)*16, p.bg2, 256, true);  // g2_2
    __syncthreads();
    {
        f32x4 a5[1][2] = {};
        mfma_tiles<1,2,8>(halfbuf, 264, p.Wg3p, 8, 0, wave, a5);
        store2_bf16(a5[0], sg + 128, 264, wave*16, p.bg3, 128, true);
    }
    __syncthreads();

    // ---- P5: w_gate = exp(sg@Wgate + bgate) --------------------------------
    if (wave == 0) {
        f32x4 a6[1][2] = {};
        mfma_tiles<1,2,8>(sg, 264, p.Wgatep, 8, 0, 0, a6);
        const int lane = tid & 63, q = lane >> 4, r = lane & 15;
        if (r < 8) {
            float bv = p.bgate[r];
#pragma unroll
            for (int mt = 0; mt < 2; ++mt)
#pragma unroll
                for (int i = 0; i < 4; ++i)
                    wgate[(mt*16 + q*4 + i)*8 + r] = expf(a6[0][mt][i] + bv);
        }
    }
    __syncthreads();

    // ---- P6: primitive loop, mixture accumulation --------------------------
    for (int i = tid; i < 32*40; i += 512) sums[i] = 0.f;
    __syncthreads();

    for (int pp = 0; pp < 8; ++pp) {
        f32x4 th[2][2] = {};
        mfma_tiles<2,2,8>(bufA, 264, p.Wp1p + (size_t)pp*65536, 8, 0, 2*wave, th);
#pragma unroll
        for (int t = 0; t < 2; ++t)
            store2_bf16(th[t], halfbuf, 264, (2*wave + t)*16, p.bp1 + pp*256, 256, true);
        __syncthreads();
        if (wave < 3) {
            f32x4 aps[1][2] = {};
            mfma_tiles<1,2,8>(halfbuf, 264, p.Wp2p + pp*12288, 8, 0, wave, aps);
            const int lane = tid & 63, q = lane >> 4, r = lane & 15;
            int col = wave*16 + r;
            float bv = (col < 40) ? p.bp2[pp*40 + col] : 0.f;
#pragma unroll
            for (int mt = 0; mt < 2; ++mt)
#pragma unroll
                for (int i = 0; i < 4; ++i)
                    psbuf[(mt*16 + q*4 + i)*48 + col] = aps[0][mt][i] + bv;
        }
        __syncthreads();
        for (int i = tid; i < 32*20; i += 512) {
            int b = i / 20, j = i - b*20;
            float invv = wgate[b*8 + pp] * expf(-psbuf[b*48 + 20 + j]);
            sums[b*40 + j]      += psbuf[b*48 + j] * invv;
            sums[b*40 + 20 + j] += invv;
        }
        __syncthreads();
    }

    // ---- P7: log_prob / entropy --------------------------------------------
    if (tid < 32) {
        int gb = b0 + tid;
        float lp = 0.f, sl = 0.f;
#pragma unroll
        for (int j = 0; j < 20; ++j) {
            float s2v = sums[tid*40 + 20 + j];
            float s1v = sums[tid*40 + j];
            float av  = p.actions[(size_t)gb*20 + j];
            float z   = av*s2v - s1v;          // (a - mu)/sigma
            float L   = logf(s2v);             // -log_sigma
            lp += -0.5f*z*z + L;
            sl += L;
        }
        p.out[(size_t)gb*2 + 0] = lp - 20.f*0.91893853320467274f;
        p.out[(size_t)gb*2 + 1] = 20.f*1.41893853320467274f - sl;
    }
}

// ---------------------------------------------------------------------------
extern "C" void kernel_launch(void* const* d_in, const int* in_sizes, int n_in,
                              void* d_out, int out_size, void* d_ws, size_t ws_size,
                              hipStream_t stream)
{
    const float* obs     = (const float*)d_in[0];
    const float* actions = (const float*)d_in[1];
    const float* W1  = (const float*)d_in[2];  const float* b1  = (const float*)d_in[3];
    const float* W2  = (const float*)d_in[4];  const float* b2  = (const float*)d_in[5];
    const float* Wp1 = (const float*)d_in[6];  const float* bp1 = (const float*)d_in[7];
    const float* Wp2 = (const float*)d_in[8];  const float* bp2 = (const float*)d_in[9];
    const float* Ws1 = (const float*)d_in[10]; const float* bs1 = (const float*)d_in[11];
    const float* Ws2 = (const float*)d_in[12]; const float* bs2 = (const float*)d_in[13];
    const float* Ws3 = (const float*)d_in[14]; const float* bs3 = (const float*)d_in[15];
    const float* Wg1 = (const float*)d_in[16]; const float* bg1 = (const float*)d_in[17];
    const float* Wg2 = (const float*)d_in[18]; const float* bg2 = (const float*)d_in[19];
    const float* Wg3 = (const float*)d_in[20]; const float* bg3 = (const float*)d_in[21];
    const float* Wgate = (const float*)d_in[22]; const float* bgate = (const float*)d_in[23];

    unsigned short* wp = (unsigned short*)d_ws;

    pack_weights<<<690, 256, 0, stream>>>(W1, W2, Wp1, Wp2, Ws1, Ws2, Ws3,
                                          Wg1, Wg2, Wg3, Wgate, wp);

    Params P;
    P.obs = obs; P.actions = actions; P.out = (float*)d_out;
    P.b1 = b1; P.b2 = b2; P.bp1 = bp1; P.bp2 = bp2;
    P.bs1 = bs1; P.bs2 = bs2; P.bs3 = bs3;
    P.bg1 = bg1; P.bg2 = bg2; P.bg3 = bg3; P.bgate = bgate;
    P.W1p = wp;            P.W2p = wp + 131072;  P.Wp1p = wp + 262144;
    P.Wp2p = wp + 786432;  P.Ws1p = wp + 884736; P.Ws2p = wp + 1015808;
    P.Ws3p = wp + 1146880; P.Wg1p = wp + 1179648; P.Wg2p = wp + 1245184;
    P.Wg3p = wp + 1376256; P.Wgatep = wp + 1409024;

    actor_fused<<<2048, 512, 0, stream>>>(P);
}